// Round 8
// baseline (366.589 us; speedup 1.0000x reference)
//
#include <hip/hip_runtime.h>
#include <hip/hip_bf16.h>
#include <stdint.h>

typedef __hip_bfloat16 bf16;
typedef short bf16x8 __attribute__((ext_vector_type(8)));
typedef float f32x4 __attribute__((ext_vector_type(4)));

#define NTOK 2048
#define HIDDEN 2880
#define KPAD 2944
#define QKVN 5120
#define QSZ 4096
#define QST 4160   // padded row stride for qb/attnb/woT
#define NH 64
#define NKV 8
#define HD 64
#define SEQ 1024

__device__ __forceinline__ void gload16(const void* g, void* l) {
  __builtin_amdgcn_global_load_lds(
      (const __attribute__((address_space(1))) uint32_t*)g,
      (__attribute__((address_space(3))) uint32_t*)l, 16, 0, 0);
}

// =====================================================================================
// prep_k: (a) w_qkv transpose->bf16 [5120][2944], (b) hidden->bf16 padded [2048][2944],
// (c) sincos tables. blocks: [0,3680) transpose, [3680,6624) cvt, [6624,6880) sincos.
// =====================================================================================
__global__ __launch_bounds__(256) void prep_k(const float* __restrict__ w_qkv,
                                              bf16* __restrict__ wqkvT,
                                              const float* __restrict__ hidden,
                                              bf16* __restrict__ hid_b,
                                              const int* __restrict__ positions,
                                              float* __restrict__ cosT,
                                              float* __restrict__ sinT) {
  __shared__ float t[64][68];
  int bid = blockIdx.x, tid = threadIdx.x;
  if (bid < 3680) {
    int tx = bid % 80, ty = bid / 80;
    int c0 = tx * 64, r0 = ty * 64;
    int lr = tid >> 2, lc4 = (tid & 3) << 4;
    int r = r0 + lr;
    if (r < HIDDEN) {
      const float* s = w_qkv + (size_t)r * QKVN + c0 + lc4;
      *(float4*)&t[lr][lc4 + 0]  = *(const float4*)(s + 0);
      *(float4*)&t[lr][lc4 + 4]  = *(const float4*)(s + 4);
      *(float4*)&t[lr][lc4 + 8]  = *(const float4*)(s + 8);
      *(float4*)&t[lr][lc4 + 12] = *(const float4*)(s + 12);
    } else {
      float4 z = make_float4(0.f, 0.f, 0.f, 0.f);
      *(float4*)&t[lr][lc4 + 0]  = z; *(float4*)&t[lr][lc4 + 4]  = z;
      *(float4*)&t[lr][lc4 + 8]  = z; *(float4*)&t[lr][lc4 + 12] = z;
    }
    __syncthreads();
    int dr = tid >> 2;
#pragma unroll
    for (int rep = 0; rep < 2; ++rep) {
      int dc0 = (tid & 3) * 16 + rep * 8;
      bf16 o[8];
#pragma unroll
      for (int k = 0; k < 8; ++k) o[k] = __float2bfloat16(t[dc0 + k][dr]);
      *(uint4*)(wqkvT + (size_t)(c0 + dr) * KPAD + r0 + dc0) = *(const uint4*)o;
    }
  } else if (bid < 6624) {
    int gpr = KPAD >> 3;
    int i = (bid - 3680) * 256 + tid;
    if (i >= NTOK * gpr) return;
    int r = i / gpr, c8 = (i - r * gpr) << 3;
    bf16 o[8];
    if (c8 < HIDDEN) {
      const float4 v0 = *(const float4*)(hidden + (size_t)r * HIDDEN + c8);
      const float4 v1 = *(const float4*)(hidden + (size_t)r * HIDDEN + c8 + 4);
      o[0] = __float2bfloat16(v0.x); o[1] = __float2bfloat16(v0.y);
      o[2] = __float2bfloat16(v0.z); o[3] = __float2bfloat16(v0.w);
      o[4] = __float2bfloat16(v1.x); o[5] = __float2bfloat16(v1.y);
      o[6] = __float2bfloat16(v1.z); o[7] = __float2bfloat16(v1.w);
    } else {
#pragma unroll
      for (int j = 0; j < 8; ++j) o[j] = __float2bfloat16(0.f);
    }
    *(uint4*)(hid_b + (size_t)r * KPAD + c8) = *(const uint4*)o;
  } else {
    int i = (bid - 6624) * 256 + tid;
    int d = i >> 11, tt = i & 2047;
    float inv = powf(150000.0f, -(float)d / 32.0f);
    float a = (float)positions[tt] * inv;
    cosT[i] = cosf(a);
    sinT[i] = sinf(a);
  }
}

// =====================================================================================
// 256x256 8-phase bf16 GEMM (T2 swizzle + T3/T4 counted vmcnt + T5 setprio)
// All 24 ds_reads of a K-tile hoisted to phase 0 (single lgkmcnt wait per K-tile);
// phases 1-3 are pure-register MFMA. Barrier/STG/vmcnt schedule identical to R6.
// EPI=0: C f32 (C0/C1 by ksplit half). EPI=2: fused RoPE epilogue + woT-transpose tail.
// =====================================================================================
#define LDALL(par) { \
  const char* _bb = lds + (((par)*4 + 2 + (wn>>1)) << 14); \
  _Pragma("unroll") \
  for (int _n = 0; _n < 4; ++_n) { \
    int _r = ((wn&1)<<6) + _n*16 + lm; \
    _Pragma("unroll") \
    for (int _kk = 0; _kk < 2; ++_kk) \
      bq[_n][_kk] = *(const bf16x8*)(_bb + _r*128 + (((_kk*4 + lg) ^ (_r & 7)) << 4)); } \
  const char* _ab = lds + (((par)*4 + wm) << 14); \
  _Pragma("unroll") \
  for (int _qc = 0; _qc < 4; ++_qc) \
  _Pragma("unroll") \
  for (int _f = 0; _f < 2; ++_f) { \
    int _r = _qc*32 + _f*16 + lm; \
    _Pragma("unroll") \
    for (int _kk = 0; _kk < 2; ++_kk) \
      af4[_qc][_f][_kk] = *(const bf16x8*)(_ab + _r*128 + (((_kk*4 + lg) ^ (_r & 7)) << 4)); } }

#define MMQ(qc) \
  _Pragma("unroll") \
  for (int _kk = 0; _kk < 2; ++_kk) \
  _Pragma("unroll") \
  for (int _f = 0; _f < 2; ++_f) \
  _Pragma("unroll") \
  for (int _n = 0; _n < 4; ++_n) \
    acc[(qc)*2 + _f][_n] = __builtin_amdgcn_mfma_f32_16x16x32_bf16( \
        af4[qc][_f][_kk], bq[_n][_kk], acc[(qc)*2 + _f][_n], 0, 0, 0);

// phase 0 of a K-tile: issue all ds_reads, stage, barrier, drain lgkm, MFMA quad 0
#define PHASE0(par, STMT, VMSTMT) { \
  LDALL(par); \
  STMT \
  __builtin_amdgcn_s_barrier(); \
  asm volatile("s_waitcnt lgkmcnt(0)" ::: "memory"); \
  __builtin_amdgcn_sched_barrier(0); \
  __builtin_amdgcn_s_setprio(1); \
  MMQ(0); \
  __builtin_amdgcn_s_setprio(0); \
  VMSTMT \
  __builtin_amdgcn_s_barrier(); }

// phases 1-3: pure-register MFMA (operands already in af4/bq)
#define PHASEN(qc, STMT, VMSTMT) { \
  STMT \
  __builtin_amdgcn_s_barrier(); \
  __builtin_amdgcn_s_setprio(1); \
  MMQ(qc); \
  __builtin_amdgcn_s_setprio(0); \
  VMSTMT \
  __builtin_amdgcn_s_barrier(); }

template<int EPI>
__global__ __launch_bounds__(512, 2) void gemm256_k(
    const bf16* __restrict__ A, const bf16* __restrict__ BT,
    float* __restrict__ C0, float* __restrict__ C1,
    bf16* __restrict__ qb, bf16* __restrict__ kb, bf16* __restrict__ vT,
    const float* __restrict__ cosT, const float* __restrict__ sinT,
    const float* __restrict__ wo, bf16* __restrict__ woT,
    int N, int ldk, int nbn, int npair, int ksplit) {
  __shared__ __align__(16) char lds[131072];
  int tid = threadIdx.x;
  int bid = blockIdx.x;

  if (EPI == 2 && bid >= 160) {
    // ---- tail blocks: transpose w_o[4096][2880] -> woT[2880][QST], 2 tiles/block ----
    int i = bid - 160;
    int half = tid >> 8;
    int t = i * 2 + half;
    int tx = t % 45, ty = t / 45;
    int c0 = tx * 64, r0 = ty * 64;
    int tid2 = tid & 255;
    float* tb = (float*)lds + half * (64 * 68);
    int lr = tid2 >> 2, lc4 = (tid2 & 3) << 4;
    const float* s = wo + (size_t)(r0 + lr) * HIDDEN + c0 + lc4;
    *(float4*)&tb[lr * 68 + lc4 + 0]  = *(const float4*)(s + 0);
    *(float4*)&tb[lr * 68 + lc4 + 4]  = *(const float4*)(s + 4);
    *(float4*)&tb[lr * 68 + lc4 + 8]  = *(const float4*)(s + 8);
    *(float4*)&tb[lr * 68 + lc4 + 12] = *(const float4*)(s + 12);
    __syncthreads();
    int dr = tid2 >> 2;
#pragma unroll
    for (int rep = 0; rep < 2; ++rep) {
      int dc0 = (tid2 & 3) * 16 + rep * 8;
      bf16 o[8];
#pragma unroll
      for (int k = 0; k < 8; ++k) o[k] = __float2bfloat16(tb[(dc0 + k) * 68 + dr]);
      *(uint4*)(woT + (size_t)(c0 + dr) * QST + r0 + dc0) = *(const uint4*)o;
    }
    return;
  }

  int l = tid & 63, lg = l >> 4, lm = l & 15;
  int w = tid >> 6, wm = w >> 2, wn = w & 3;
  int kbeg = 0;
  float* C = C0;
  if (ksplit) {
    int half = gridDim.x >> 1;
    if (bid >= half) { bid -= half; kbeg = ksplit; C = C1; }
  }
  int bm = bid / nbn, bn = bid - bm * nbn;
  int m0 = bm << 8, n0 = bn << 8;
  int Bmax = N - 1;
  f32x4 acc[8][4] = {};
  bf16x8 bq[4][2];
  bf16x8 af4[4][2][2];

  auto STG = [&](int slot, const bf16* mat, int rowBase, int rowMax, int kbase) {
#pragma unroll
    for (int rep = 0; rep < 2; ++rep) {
      int gi = (rep << 9) + tid;
      int row = gi >> 3, g = gi & 7;
      int gr = rowBase + row; if (gr > rowMax) gr = rowMax;
      gload16(mat + (size_t)gr * ldk + kbase + ((g ^ (row & 7)) << 3),
              lds + slot * 16384 + gi * 16);
    }
  };

  STG(0, A, m0, 2047, kbeg);
  STG(1, A, m0 + 128, 2047, kbeg);
  STG(2, BT, n0, Bmax, kbeg);
  STG(3, BT, n0 + 128, Bmax, kbeg);
  STG(6, BT, n0, Bmax, kbeg + 64);
  STG(7, BT, n0 + 128, Bmax, kbeg + 64);
  asm volatile("s_waitcnt vmcnt(4)" ::: "memory");
  __builtin_amdgcn_s_barrier();

  for (int i = 0; i < npair; ++i) {
    int kt = kbeg + (i << 7);
    bool pf = (i + 1 < npair);
    // K-tile kt (parity 0)
    PHASE0(0, { STG(4, A, m0, 2047, kt + 64); }, ;)
    PHASEN(1, { STG(5, A, m0 + 128, 2047, kt + 64); }, ;)
    PHASEN(2, { if (pf) STG(2, BT, n0, Bmax, kt + 128); }, ;)
    PHASEN(3, { if (pf) STG(3, BT, n0 + 128, Bmax, kt + 128); },
           { if (pf) { asm volatile("s_waitcnt vmcnt(4)" ::: "memory"); }
             else    { asm volatile("s_waitcnt vmcnt(0)" ::: "memory"); } })
    // K-tile kt+64 (parity 1)
    PHASE0(1, { if (pf) STG(0, A, m0, 2047, kt + 128); }, ;)
    PHASEN(1, { if (pf) STG(1, A, m0 + 128, 2047, kt + 128); }, ;)
    PHASEN(2, { if (pf) STG(6, BT, n0, Bmax, kt + 192); }, ;)
    PHASEN(3, { if (pf) STG(7, BT, n0 + 128, Bmax, kt + 192); },
           { if (pf) { asm volatile("s_waitcnt vmcnt(4)" ::: "memory"); } })
  }

  if (EPI == 2) {
    // fused RoPE + layout epilogue. Wave owns head-slot h64 = bn*4 + wn.
    int h64 = (n0 >> 6) + wn;
    int tbase = m0 + (wm << 7) + lg * 4;
    if (h64 < 72) {
      bool isK = (h64 >= 64);
      bf16* outp = isK ? kb : qb;
      size_t ostr = isK ? 512 : QST;
      int hd0 = (isK ? (h64 - 64) : h64) << 6;
      float scl = isK ? 1.0f : 0.125f;
#pragma unroll
      for (int nf = 0; nf < 2; ++nf) {
        int d31 = nf * 16 + lm;
        const float* ct = cosT + (size_t)d31 * 2048;
        const float* st = sinT + (size_t)d31 * 2048;
#pragma unroll
        for (int mf = 0; mf < 8; ++mf) {
          int t0 = tbase + mf * 16;
          float4 c4 = *(const float4*)(ct + t0);
          float4 s4 = *(const float4*)(st + t0);
          float cc[4] = {c4.x, c4.y, c4.z, c4.w};
          float ss[4] = {s4.x, s4.y, s4.z, s4.w};
#pragma unroll
          for (int j = 0; j < 4; ++j) {
            float x1 = acc[mf][nf][j], x2 = acc[mf][nf + 2][j];
            outp[(size_t)(t0 + j) * ostr + hd0 + d31] =
                __float2bfloat16((x1 * cc[j] - x2 * ss[j]) * scl);
            outp[(size_t)(t0 + j) * ostr + hd0 + d31 + 32] =
                __float2bfloat16((x2 * cc[j] + x1 * ss[j]) * scl);
          }
        }
      }
    } else {
      int kvh = h64 - 72;
#pragma unroll
      for (int nf = 0; nf < 4; ++nf) {
        int d = nf * 16 + lm;
#pragma unroll
        for (int mf = 0; mf < 8; ++mf) {
          int t = tbase + mf * 16;          // j=0..3 are s-contiguous in vT
          int b = t >> 10, s = t & 1023;
          bf16 o[4];
#pragma unroll
          for (int j = 0; j < 4; ++j) o[j] = __float2bfloat16(acc[mf][nf][j]);
          *(uint2*)&vT[((size_t)(b * 8 + kvh) * 64 + d) * 1024 + s] = *(const uint2*)o;
        }
      }
    }
    return;
  }

#pragma unroll
  for (int mf = 0; mf < 8; ++mf)
#pragma unroll
    for (int nf = 0; nf < 4; ++nf) {
      int col = n0 + (wn << 6) + nf * 16 + lm;
      if (col >= N) continue;
      int row = m0 + (wm << 7) + mf * 16 + lg * 4;
#pragma unroll
      for (int j = 0; j < 4; ++j)
        C[(size_t)(row + j) * N + col] = acc[mf][nf][j];
    }
}

// ---------------- flash attention, sliding window 128, sinks ----------------
__global__ __launch_bounds__(256) void attn_k(const bf16* __restrict__ Q,
                                              const bf16* __restrict__ Kg,
                                              const bf16* __restrict__ VT,
                                              const float* __restrict__ sinks,
                                              bf16* __restrict__ Og) {
  __shared__ __align__(16) bf16 Qs[128 * 64];
  __shared__ __align__(16) bf16 Ks[128 * 64];
  __shared__ __align__(16) bf16 Vs[64 * 128];
  __shared__ __align__(16) bf16 Ps[4][32 * 128];
  int bid = blockIdx.x;
  int b = bid >> 9, rest = bid & 511, h = rest >> 3, qt = rest & 7;
  int q0 = qt * 128, kvh = h >> 3;
  int tid = threadIdx.x, w = tid >> 6, l = tid & 63, lg = l >> 4, lm = l & 15;

  float mrun[2][4], lrun[2][4];
  float ls = __logf(sinks[h]);
#pragma unroll
  for (int mi = 0; mi < 2; ++mi)
#pragma unroll
    for (int j = 0; j < 4; ++j) { mrun[mi][j] = ls; lrun[mi][j] = 1.0f; }
  f32x4 oacc[2][4] = {};

#pragma unroll
  for (int g = 0; g < 4; ++g) {
    int c = g * 256 + w * 64 + l;
    int r = c >> 3, kc = (c & 7) * 8;
    gload16(Q + ((size_t)(b * 1024 + q0 + r)) * QST + h * 64 + kc,
            (char*)Qs + (size_t)(g * 256 + w * 64) * 16);
  }

  for (int t = (q0 == 0) ? 1 : 0; t < 2; ++t) {
    int kb = q0 - 128 + t * 128;
#pragma unroll
    for (int g = 0; g < 4; ++g) {
      int c = g * 256 + w * 64 + l;
      int r = c >> 3, kc = (c & 7) * 8;
      gload16(Kg + ((size_t)(b * 1024 + kb + r)) * 512 + kvh * 64 + kc,
              (char*)Ks + (size_t)(g * 256 + w * 64) * 16);
      int rv = c >> 4, kv = (c & 15) * 8;
      gload16(VT + ((size_t)(b * 8 + kvh) * 64 + rv) * 1024 + kb + kv,
              (char*)Vs + (size_t)(g * 256 + w * 64) * 16);
    }
    __syncthreads();

    f32x4 sacc[2][8] = {};
#pragma unroll
    for (int kk = 0; kk < 2; ++kk) {
      bf16x8 qf[2], kf[8];
#pragma unroll
      for (int mi = 0; mi < 2; ++mi)
        qf[mi] = *reinterpret_cast<const bf16x8*>(&Qs[(w * 32 + mi * 16 + lm) * 64 + kk * 32 + lg * 8]);
#pragma unroll
      for (int ni = 0; ni < 8; ++ni)
        kf[ni] = *reinterpret_cast<const bf16x8*>(&Ks[(ni * 16 + lm) * 64 + kk * 32 + lg * 8]);
#pragma unroll
      for (int mi = 0; mi < 2; ++mi)
#pragma unroll
        for (int ni = 0; ni < 8; ++ni)
          sacc[mi][ni] = __builtin_amdgcn_mfma_f32_16x16x32_bf16(qf[mi], kf[ni], sacc[mi][ni], 0, 0, 0);
    }

#pragma unroll
    for (int mi = 0; mi < 2; ++mi)
#pragma unroll
      for (int j = 0; j < 4; ++j) {
        int qi = q0 + w * 32 + mi * 16 + lg * 4 + j;
        float mx = -1e30f;
#pragma unroll
        for (int ni = 0; ni < 8; ++ni) {
          int kg = kb + ni * 16 + lm;
          float v = sacc[mi][ni][j];
          v = (kg <= qi && kg >= qi - 127) ? v : -1e30f;
          sacc[mi][ni][j] = v;
          mx = fmaxf(mx, v);
        }
#pragma unroll
        for (int d = 1; d < 16; d <<= 1) mx = fmaxf(mx, __shfl_xor(mx, d, 64));
        float mnew = fmaxf(mrun[mi][j], mx);
        float sum = 0.f;
#pragma unroll
        for (int ni = 0; ni < 8; ++ni) {
          float p = __expf(sacc[mi][ni][j] - mnew);
          sacc[mi][ni][j] = p;
          sum += p;
        }
#pragma unroll
        for (int d = 1; d < 16; d <<= 1) sum += __shfl_xor(sum, d, 64);
        float alpha = __expf(mrun[mi][j] - mnew);
        lrun[mi][j] = lrun[mi][j] * alpha + sum;
        mrun[mi][j] = mnew;
#pragma unroll
        for (int ni = 0; ni < 4; ++ni) oacc[mi][ni][j] *= alpha;
#pragma unroll
        for (int ni = 0; ni < 8; ++ni)
          Ps[w][(mi * 16 + lg * 4 + j) * 128 + ni * 16 + lm] = __float2bfloat16(sacc[mi][ni][j]);
      }

#pragma unroll
    for (int ks = 0; ks < 4; ++ks) {
      bf16x8 pf[2], vf[4];
#pragma unroll
      for (int mi = 0; mi < 2; ++mi)
        pf[mi] = *reinterpret_cast<const bf16x8*>(&Ps[w][(mi * 16 + lm) * 128 + ks * 32 + lg * 8]);
#pragma unroll
      for (int ni = 0; ni < 4; ++ni)
        vf[ni] = *reinterpret_cast<const bf16x8*>(&Vs[(ni * 16 + lm) * 128 + ks * 32 + lg * 8]);
#pragma unroll
      for (int mi = 0; mi < 2; ++mi)
#pragma unroll
        for (int ni = 0; ni < 4; ++ni)
          oacc[mi][ni] = __builtin_amdgcn_mfma_f32_16x16x32_bf16(pf[mi], vf[ni], oacc[mi][ni], 0, 0, 0);
    }
    __syncthreads();
  }

#pragma unroll
  for (int mi = 0; mi < 2; ++mi)
#pragma unroll
    for (int ni = 0; ni < 4; ++ni)
#pragma unroll
      for (int j = 0; j < 4; ++j) {
        int tok = b * 1024 + q0 + w * 32 + mi * 16 + lg * 4 + j;
        Og[(size_t)tok * QST + h * 64 + ni * 16 + lm] =
            __float2bfloat16(oacc[mi][ni][j] / lrun[mi][j]);
      }
}

// ---------------- add two f32 partials -> f32 out ----------------
__global__ __launch_bounds__(256) void add2_k(const float* __restrict__ a,
                                              const float* __restrict__ b,
                                              float* __restrict__ o, int n4) {
  int i = blockIdx.x * 256 + threadIdx.x;
  if (i >= n4) return;
  float4 x = reinterpret_cast<const float4*>(a)[i];
  float4 y = reinterpret_cast<const float4*>(b)[i];
  reinterpret_cast<float4*>(o)[i] = make_float4(x.x + y.x, x.y + y.y, x.z + y.z, x.w + y.w);
}

extern "C" void kernel_launch(void* const* d_in, const int* in_sizes, int n_in,
                              void* d_out, int out_size, void* d_ws, size_t ws_size,
                              hipStream_t stream) {
  const int*   positions = (const int*)d_in[0];
  const float* hidden    = (const float*)d_in[1];
  const float* w_qkv     = (const float*)d_in[2];
  const float* w_o       = (const float*)d_in[3];
  const float* sinks     = (const float*)d_in[4];
  float* out = (float*)d_out;

  char* ws = (char*)d_ws;
  bf16*  wqkvT = (bf16*)(ws + 0);            // [5120][2944]  = 30,146,560 (dead after QKV)
  bf16*  woT   = (bf16*)(ws + 30146560);     // [2880][4160]  = 23,961,600
  bf16*  qb    = (bf16*)(ws + 54108160);     // [2048][4160]  = 17,039,360
  bf16*  kb    = (bf16*)(ws + 71147520);     // [2048][512]   =  2,097,152
  bf16*  vT    = (bf16*)(ws + 73244672);     // [16*64][1024] =  2,097,152
  bf16*  attnb = (bf16*)(ws + 75341824);     // [2048][4160]  = 17,039,360
  bf16*  hid_b = (bf16*)(ws + 92381184);     // [2048][2944]  = 12,058,624 (dead after QKV)
  float* cosT  = (float*)(ws + 104439808);   // 262,144 (dead after QKV)
  float* sinT  = (float*)(ws + 104701952);   // 262,144 (dead after QKV)
  float* Cp0   = (float*)(ws + 92381184);    // overlay hid_b/cosT/sinT
  float* Cp1   = (float*)(ws + 0);           // overlay wqkvT

  // 1. fused prep: w_qkv transpose + hidden cvt/pad + sincos tables
  prep_k<<<6880, 256, 0, stream>>>(w_qkv, wqkvT, hidden, hid_b, positions, cosT, sinT);
  // 2. QKV projection + fused RoPE/layout epilogue; tail blocks transpose w_o -> woT
  gemm256_k<2><<<160 + 1440, 512, 0, stream>>>(
      hid_b, wqkvT, nullptr, nullptr, qb, kb, vT, cosT, sinT, w_o, woT,
      QKVN, KPAD, QKVN / 256, KPAD / 128, 0);
  // 3. attention
  attn_k<<<2 * NH * (SEQ / 128), 256, 0, stream>>>(qb, kb, vT, sinks, attnb);
  // 4. output projection with 2-way K-split -> 2 f32 partials
  gemm256_k<0><<<2 * (NTOK / 256) * 12, 512, 0, stream>>>(
      attnb, woT, Cp0, Cp1, nullptr, nullptr, nullptr, nullptr, nullptr, nullptr, nullptr,
      HIDDEN, QST, 12, 16, 2048);
  // 5. partial sum -> out
  add2_k<<<(NTOK * HIDDEN / 4) / 256, 256, 0, stream>>>(Cp0, Cp1, out, NTOK * HIDDEN / 4);
}

// Round 9
// 224.389 us; speedup vs baseline: 1.6337x; 1.6337x over previous
//
#include <hip/hip_runtime.h>
#include <hip/hip_bf16.h>
#include <stdint.h>

typedef __hip_bfloat16 bf16;
typedef short bf16x8 __attribute__((ext_vector_type(8)));
typedef float f32x4 __attribute__((ext_vector_type(4)));

#define NTOK 2048
#define HIDDEN 2880
#define KPAD 2944
#define QKVN 5120
#define QSZ 4096
#define QST 4160   // padded row stride for qb/attnb/woT
#define NH 64
#define NKV 8
#define HD 64
#define SEQ 1024

__device__ __forceinline__ void gload16(const void* g, void* l) {
  __builtin_amdgcn_global_load_lds(
      (const __attribute__((address_space(1))) uint32_t*)g,
      (__attribute__((address_space(3))) uint32_t*)l, 16, 0, 0);
}

// =====================================================================================
// prep_k: (a) w_qkv transpose->bf16 [5120][2944], (b) hidden->bf16 padded [2048][2944],
// (c) sincos tables. blocks: [0,3680) transpose, [3680,6624) cvt, [6624,6880) sincos.
// =====================================================================================
__global__ __launch_bounds__(256) void prep_k(const float* __restrict__ w_qkv,
                                              bf16* __restrict__ wqkvT,
                                              const float* __restrict__ hidden,
                                              bf16* __restrict__ hid_b,
                                              const int* __restrict__ positions,
                                              float* __restrict__ cosT,
                                              float* __restrict__ sinT) {
  __shared__ float t[64][68];
  int bid = blockIdx.x, tid = threadIdx.x;
  if (bid < 3680) {
    int tx = bid % 80, ty = bid / 80;
    int c0 = tx * 64, r0 = ty * 64;
    int lr = tid >> 2, lc4 = (tid & 3) << 4;
    int r = r0 + lr;
    if (r < HIDDEN) {
      const float* s = w_qkv + (size_t)r * QKVN + c0 + lc4;
      *(float4*)&t[lr][lc4 + 0]  = *(const float4*)(s + 0);
      *(float4*)&t[lr][lc4 + 4]  = *(const float4*)(s + 4);
      *(float4*)&t[lr][lc4 + 8]  = *(const float4*)(s + 8);
      *(float4*)&t[lr][lc4 + 12] = *(const float4*)(s + 12);
    } else {
      float4 z = make_float4(0.f, 0.f, 0.f, 0.f);
      *(float4*)&t[lr][lc4 + 0]  = z; *(float4*)&t[lr][lc4 + 4]  = z;
      *(float4*)&t[lr][lc4 + 8]  = z; *(float4*)&t[lr][lc4 + 12] = z;
    }
    __syncthreads();
    int dr = tid >> 2;
#pragma unroll
    for (int rep = 0; rep < 2; ++rep) {
      int dc0 = (tid & 3) * 16 + rep * 8;
      bf16 o[8];
#pragma unroll
      for (int k = 0; k < 8; ++k) o[k] = __float2bfloat16(t[dc0 + k][dr]);
      *(uint4*)(wqkvT + (size_t)(c0 + dr) * KPAD + r0 + dc0) = *(const uint4*)o;
    }
  } else if (bid < 6624) {
    int gpr = KPAD >> 3;
    int i = (bid - 3680) * 256 + tid;
    if (i >= NTOK * gpr) return;
    int r = i / gpr, c8 = (i - r * gpr) << 3;
    bf16 o[8];
    if (c8 < HIDDEN) {
      const float4 v0 = *(const float4*)(hidden + (size_t)r * HIDDEN + c8);
      const float4 v1 = *(const float4*)(hidden + (size_t)r * HIDDEN + c8 + 4);
      o[0] = __float2bfloat16(v0.x); o[1] = __float2bfloat16(v0.y);
      o[2] = __float2bfloat16(v0.z); o[3] = __float2bfloat16(v0.w);
      o[4] = __float2bfloat16(v1.x); o[5] = __float2bfloat16(v1.y);
      o[6] = __float2bfloat16(v1.z); o[7] = __float2bfloat16(v1.w);
    } else {
#pragma unroll
      for (int j = 0; j < 8; ++j) o[j] = __float2bfloat16(0.f);
    }
    *(uint4*)(hid_b + (size_t)r * KPAD + c8) = *(const uint4*)o;
  } else {
    int i = (bid - 6624) * 256 + tid;
    int d = i >> 11, tt = i & 2047;
    float inv = powf(150000.0f, -(float)d / 32.0f);
    float a = (float)positions[tt] * inv;
    cosT[i] = cosf(a);
    sinT[i] = sinf(a);
  }
}

// =====================================================================================
// 256x256 8-phase bf16 GEMM (T2 swizzle + T3/T4 counted vmcnt + T5 setprio)
// Counted lgkmcnt(4) + 2-deep A-fragment ping-pong (afA/afB): each A-quad's LDS
// latency hides under the previous MFMA cluster. Barrier/STG/vmcnt schedule = R6.
// EPI=0: C f32 (C0/C1 by ksplit half). EPI=2: fused RoPE epilogue + woT-transpose tail.
// =====================================================================================
#define LDB(par) { \
  const char* _bb = lds + (((par)*4 + 2 + (wn>>1)) << 14); \
  _Pragma("unroll") \
  for (int _n = 0; _n < 4; ++_n) { \
    int _r = ((wn&1)<<6) + _n*16 + lm; \
    _Pragma("unroll") \
    for (int _kk = 0; _kk < 2; ++_kk) \
      bq[_n][_kk] = *(const bf16x8*)(_bb + _r*128 + (((_kk*4 + lg) ^ (_r & 7)) << 4)); } }

#define LDA(par, qc, dst) { \
  const char* _ab = lds + (((par)*4 + wm) << 14); \
  _Pragma("unroll") \
  for (int _f = 0; _f < 2; ++_f) { \
    int _r = (qc)*32 + _f*16 + lm; \
    _Pragma("unroll") \
    for (int _kk = 0; _kk < 2; ++_kk) \
      dst[_f][_kk] = *(const bf16x8*)(_ab + _r*128 + (((_kk*4 + lg) ^ (_r & 7)) << 4)); } }

#define MMQ(qc, A_) \
  _Pragma("unroll") \
  for (int _kk = 0; _kk < 2; ++_kk) \
  _Pragma("unroll") \
  for (int _f = 0; _f < 2; ++_f) \
  _Pragma("unroll") \
  for (int _n = 0; _n < 4; ++_n) \
    acc[(qc)*2 + _f][_n] = __builtin_amdgcn_mfma_f32_16x16x32_bf16( \
        A_[_f][_kk], bq[_n][_kk], acc[(qc)*2 + _f][_n], 0, 0, 0);

#define WAIT4 asm volatile("s_waitcnt lgkmcnt(4)" ::: "memory"); __builtin_amdgcn_sched_barrier(0);
#define WAIT0 asm volatile("s_waitcnt lgkmcnt(0)" ::: "memory"); __builtin_amdgcn_sched_barrier(0);
#define BAR __builtin_amdgcn_s_barrier();
#define PRIO1 __builtin_amdgcn_s_setprio(1);
#define PRIO0 __builtin_amdgcn_s_setprio(0);

// One K-tile (64 wide) = 4 phases. S0..S3 staging stmts, VM3 the vmcnt stmt.
#define KTILE(par, S0, S1, S2, S3, VM3) { \
  LDB(par); LDA(par, 0, afA); LDA(par, 1, afB); \
  S0 \
  BAR WAIT4 PRIO1 MMQ(0, afA) PRIO0 BAR \
  LDA(par, 2, afA); \
  S1 \
  BAR WAIT4 PRIO1 MMQ(1, afB) PRIO0 BAR \
  LDA(par, 3, afB); \
  S2 \
  BAR WAIT4 PRIO1 MMQ(2, afA) PRIO0 BAR \
  S3 \
  BAR WAIT0 PRIO1 MMQ(3, afB) PRIO0 VM3 BAR }

template<int EPI>
__global__ __launch_bounds__(512, 2) void gemm256_k(
    const bf16* __restrict__ A, const bf16* __restrict__ BT,
    float* __restrict__ C0, float* __restrict__ C1,
    bf16* __restrict__ qb, bf16* __restrict__ kb, bf16* __restrict__ vT,
    const float* __restrict__ cosT, const float* __restrict__ sinT,
    const float* __restrict__ wo, bf16* __restrict__ woT,
    int N, int ldk, int nbn, int npair, int ksplit) {
  __shared__ __align__(16) char lds[131072];
  int tid = threadIdx.x;
  int bid = blockIdx.x;

  if (EPI == 2 && bid >= 160) {
    // ---- tail blocks: transpose w_o[4096][2880] -> woT[2880][QST], 2 tiles/block ----
    int i = bid - 160;
    int half = tid >> 8;
    int t = i * 2 + half;
    int tx = t % 45, ty = t / 45;
    int c0 = tx * 64, r0 = ty * 64;
    int tid2 = tid & 255;
    float* tb = (float*)lds + half * (64 * 68);
    int lr = tid2 >> 2, lc4 = (tid2 & 3) << 4;
    const float* s = wo + (size_t)(r0 + lr) * HIDDEN + c0 + lc4;
    *(float4*)&tb[lr * 68 + lc4 + 0]  = *(const float4*)(s + 0);
    *(float4*)&tb[lr * 68 + lc4 + 4]  = *(const float4*)(s + 4);
    *(float4*)&tb[lr * 68 + lc4 + 8]  = *(const float4*)(s + 8);
    *(float4*)&tb[lr * 68 + lc4 + 12] = *(const float4*)(s + 12);
    __syncthreads();
    int dr = tid2 >> 2;
#pragma unroll
    for (int rep = 0; rep < 2; ++rep) {
      int dc0 = (tid2 & 3) * 16 + rep * 8;
      bf16 o[8];
#pragma unroll
      for (int k = 0; k < 8; ++k) o[k] = __float2bfloat16(tb[(dc0 + k) * 68 + dr]);
      *(uint4*)(woT + (size_t)(c0 + dr) * QST + r0 + dc0) = *(const uint4*)o;
    }
    return;
  }

  int l = tid & 63, lg = l >> 4, lm = l & 15;
  int w = tid >> 6, wm = w >> 2, wn = w & 3;
  int kbeg = 0;
  float* C = C0;
  if (ksplit) {
    int half = gridDim.x >> 1;
    if (bid >= half) { bid -= half; kbeg = ksplit; C = C1; }
  }
  int bm = bid / nbn, bn = bid - bm * nbn;
  int m0 = bm << 8, n0 = bn << 8;
  int Bmax = N - 1;
  f32x4 acc[8][4] = {};
  bf16x8 bq[4][2];
  bf16x8 afA[2][2], afB[2][2];

  auto STG = [&](int slot, const bf16* mat, int rowBase, int rowMax, int kbase) {
#pragma unroll
    for (int rep = 0; rep < 2; ++rep) {
      int gi = (rep << 9) + tid;
      int row = gi >> 3, g = gi & 7;
      int gr = rowBase + row; if (gr > rowMax) gr = rowMax;
      gload16(mat + (size_t)gr * ldk + kbase + ((g ^ (row & 7)) << 3),
              lds + slot * 16384 + gi * 16);
    }
  };

  STG(0, A, m0, 2047, kbeg);
  STG(1, A, m0 + 128, 2047, kbeg);
  STG(2, BT, n0, Bmax, kbeg);
  STG(3, BT, n0 + 128, Bmax, kbeg);
  STG(6, BT, n0, Bmax, kbeg + 64);
  STG(7, BT, n0 + 128, Bmax, kbeg + 64);
  asm volatile("s_waitcnt vmcnt(4)" ::: "memory");
  __builtin_amdgcn_s_barrier();

  for (int i = 0; i < npair; ++i) {
    int kt = kbeg + (i << 7);
    bool pf = (i + 1 < npair);
    // K-tile kt (parity 0)
    KTILE(0,
          { STG(4, A, m0, 2047, kt + 64); },
          { STG(5, A, m0 + 128, 2047, kt + 64); },
          { if (pf) STG(2, BT, n0, Bmax, kt + 128); },
          { if (pf) STG(3, BT, n0 + 128, Bmax, kt + 128); },
          { if (pf) { asm volatile("s_waitcnt vmcnt(4)" ::: "memory"); }
            else    { asm volatile("s_waitcnt vmcnt(0)" ::: "memory"); } })
    // K-tile kt+64 (parity 1)
    KTILE(1,
          { if (pf) STG(0, A, m0, 2047, kt + 128); },
          { if (pf) STG(1, A, m0 + 128, 2047, kt + 128); },
          { if (pf) STG(6, BT, n0, Bmax, kt + 192); },
          { if (pf) STG(7, BT, n0 + 128, Bmax, kt + 192); },
          { if (pf) { asm volatile("s_waitcnt vmcnt(4)" ::: "memory"); } })
  }

  if (EPI == 2) {
    // fused RoPE + layout epilogue. Wave owns head-slot h64 = bn*4 + wn.
    int h64 = (n0 >> 6) + wn;
    int tbase = m0 + (wm << 7) + lg * 4;
    if (h64 < 72) {
      bool isK = (h64 >= 64);
      bf16* outp = isK ? kb : qb;
      size_t ostr = isK ? 512 : QST;
      int hd0 = (isK ? (h64 - 64) : h64) << 6;
      float scl = isK ? 1.0f : 0.125f;
#pragma unroll
      for (int nf = 0; nf < 2; ++nf) {
        int d31 = nf * 16 + lm;
        const float* ct = cosT + (size_t)d31 * 2048;
        const float* st = sinT + (size_t)d31 * 2048;
#pragma unroll
        for (int mf = 0; mf < 8; ++mf) {
          int t0 = tbase + mf * 16;
          float4 c4 = *(const float4*)(ct + t0);
          float4 s4 = *(const float4*)(st + t0);
          float cc[4] = {c4.x, c4.y, c4.z, c4.w};
          float ss[4] = {s4.x, s4.y, s4.z, s4.w};
#pragma unroll
          for (int j = 0; j < 4; ++j) {
            float x1 = acc[mf][nf][j], x2 = acc[mf][nf + 2][j];
            outp[(size_t)(t0 + j) * ostr + hd0 + d31] =
                __float2bfloat16((x1 * cc[j] - x2 * ss[j]) * scl);
            outp[(size_t)(t0 + j) * ostr + hd0 + d31 + 32] =
                __float2bfloat16((x2 * cc[j] + x1 * ss[j]) * scl);
          }
        }
      }
    } else {
      int kvh = h64 - 72;
#pragma unroll
      for (int nf = 0; nf < 4; ++nf) {
        int d = nf * 16 + lm;
#pragma unroll
        for (int mf = 0; mf < 8; ++mf) {
          int t = tbase + mf * 16;          // j=0..3 are s-contiguous in vT
          int b = t >> 10, s = t & 1023;
          bf16 o[4];
#pragma unroll
          for (int j = 0; j < 4; ++j) o[j] = __float2bfloat16(acc[mf][nf][j]);
          *(uint2*)&vT[((size_t)(b * 8 + kvh) * 64 + d) * 1024 + s] = *(const uint2*)o;
        }
      }
    }
    return;
  }

#pragma unroll
  for (int mf = 0; mf < 8; ++mf)
#pragma unroll
    for (int nf = 0; nf < 4; ++nf) {
      int col = n0 + (wn << 6) + nf * 16 + lm;
      if (col >= N) continue;
      int row = m0 + (wm << 7) + mf * 16 + lg * 4;
#pragma unroll
      for (int j = 0; j < 4; ++j)
        C[(size_t)(row + j) * N + col] = acc[mf][nf][j];
    }
}

// ---------------- flash attention, sliding window 128, sinks ----------------
__global__ __launch_bounds__(256) void attn_k(const bf16* __restrict__ Q,
                                              const bf16* __restrict__ Kg,
                                              const bf16* __restrict__ VT,
                                              const float* __restrict__ sinks,
                                              bf16* __restrict__ Og) {
  __shared__ __align__(16) bf16 Qs[128 * 64];
  __shared__ __align__(16) bf16 Ks[128 * 64];
  __shared__ __align__(16) bf16 Vs[64 * 128];
  __shared__ __align__(16) bf16 Ps[4][32 * 128];
  int bid = blockIdx.x;
  int b = bid >> 9, rest = bid & 511, h = rest >> 3, qt = rest & 7;
  int q0 = qt * 128, kvh = h >> 3;
  int tid = threadIdx.x, w = tid >> 6, l = tid & 63, lg = l >> 4, lm = l & 15;

  float mrun[2][4], lrun[2][4];
  float ls = __logf(sinks[h]);
#pragma unroll
  for (int mi = 0; mi < 2; ++mi)
#pragma unroll
    for (int j = 0; j < 4; ++j) { mrun[mi][j] = ls; lrun[mi][j] = 1.0f; }
  f32x4 oacc[2][4] = {};

#pragma unroll
  for (int g = 0; g < 4; ++g) {
    int c = g * 256 + w * 64 + l;
    int r = c >> 3, kc = (c & 7) * 8;
    gload16(Q + ((size_t)(b * 1024 + q0 + r)) * QST + h * 64 + kc,
            (char*)Qs + (size_t)(g * 256 + w * 64) * 16);
  }

  for (int t = (q0 == 0) ? 1 : 0; t < 2; ++t) {
    int kb = q0 - 128 + t * 128;
#pragma unroll
    for (int g = 0; g < 4; ++g) {
      int c = g * 256 + w * 64 + l;
      int r = c >> 3, kc = (c & 7) * 8;
      gload16(Kg + ((size_t)(b * 1024 + kb + r)) * 512 + kvh * 64 + kc,
              (char*)Ks + (size_t)(g * 256 + w * 64) * 16);
      int rv = c >> 4, kv = (c & 15) * 8;
      gload16(VT + ((size_t)(b * 8 + kvh) * 64 + rv) * 1024 + kb + kv,
              (char*)Vs + (size_t)(g * 256 + w * 64) * 16);
    }
    __syncthreads();

    f32x4 sacc[2][8] = {};
#pragma unroll
    for (int kk = 0; kk < 2; ++kk) {
      bf16x8 qf[2], kf[8];
#pragma unroll
      for (int mi = 0; mi < 2; ++mi)
        qf[mi] = *reinterpret_cast<const bf16x8*>(&Qs[(w * 32 + mi * 16 + lm) * 64 + kk * 32 + lg * 8]);
#pragma unroll
      for (int ni = 0; ni < 8; ++ni)
        kf[ni] = *reinterpret_cast<const bf16x8*>(&Ks[(ni * 16 + lm) * 64 + kk * 32 + lg * 8]);
#pragma unroll
      for (int mi = 0; mi < 2; ++mi)
#pragma unroll
        for (int ni = 0; ni < 8; ++ni)
          sacc[mi][ni] = __builtin_amdgcn_mfma_f32_16x16x32_bf16(qf[mi], kf[ni], sacc[mi][ni], 0, 0, 0);
    }

#pragma unroll
    for (int mi = 0; mi < 2; ++mi)
#pragma unroll
      for (int j = 0; j < 4; ++j) {
        int qi = q0 + w * 32 + mi * 16 + lg * 4 + j;
        float mx = -1e30f;
#pragma unroll
        for (int ni = 0; ni < 8; ++ni) {
          int kg = kb + ni * 16 + lm;
          float v = sacc[mi][ni][j];
          v = (kg <= qi && kg >= qi - 127) ? v : -1e30f;
          sacc[mi][ni][j] = v;
          mx = fmaxf(mx, v);
        }
#pragma unroll
        for (int d = 1; d < 16; d <<= 1) mx = fmaxf(mx, __shfl_xor(mx, d, 64));
        float mnew = fmaxf(mrun[mi][j], mx);
        float sum = 0.f;
#pragma unroll
        for (int ni = 0; ni < 8; ++ni) {
          float p = __expf(sacc[mi][ni][j] - mnew);
          sacc[mi][ni][j] = p;
          sum += p;
        }
#pragma unroll
        for (int d = 1; d < 16; d <<= 1) sum += __shfl_xor(sum, d, 64);
        float alpha = __expf(mrun[mi][j] - mnew);
        lrun[mi][j] = lrun[mi][j] * alpha + sum;
        mrun[mi][j] = mnew;
#pragma unroll
        for (int ni = 0; ni < 4; ++ni) oacc[mi][ni][j] *= alpha;
#pragma unroll
        for (int ni = 0; ni < 8; ++ni)
          Ps[w][(mi * 16 + lg * 4 + j) * 128 + ni * 16 + lm] = __float2bfloat16(sacc[mi][ni][j]);
      }

#pragma unroll
    for (int ks = 0; ks < 4; ++ks) {
      bf16x8 pf[2], vf[4];
#pragma unroll
      for (int mi = 0; mi < 2; ++mi)
        pf[mi] = *reinterpret_cast<const bf16x8*>(&Ps[w][(mi * 16 + lm) * 128 + ks * 32 + lg * 8]);
#pragma unroll
      for (int ni = 0; ni < 4; ++ni)
        vf[ni] = *reinterpret_cast<const bf16x8*>(&Vs[(ni * 16 + lm) * 128 + ks * 32 + lg * 8]);
#pragma unroll
      for (int mi = 0; mi < 2; ++mi)
#pragma unroll
        for (int ni = 0; ni < 4; ++ni)
          oacc[mi][ni] = __builtin_amdgcn_mfma_f32_16x16x32_bf16(pf[mi], vf[ni], oacc[mi][ni], 0, 0, 0);
    }
    __syncthreads();
  }

#pragma unroll
  for (int mi = 0; mi < 2; ++mi)
#pragma unroll
    for (int ni = 0; ni < 4; ++ni)
#pragma unroll
      for (int j = 0; j < 4; ++j) {
        int tok = b * 1024 + q0 + w * 32 + mi * 16 + lg * 4 + j;
        Og[(size_t)tok * QST + h * 64 + ni * 16 + lm] =
            __float2bfloat16(oacc[mi][ni][j] / lrun[mi][j]);
      }
}

// ---------------- add two f32 partials -> f32 out ----------------
__global__ __launch_bounds__(256) void add2_k(const float* __restrict__ a,
                                              const float* __restrict__ b,
                                              float* __restrict__ o, int n4) {
  int i = blockIdx.x * 256 + threadIdx.x;
  if (i >= n4) return;
  float4 x = reinterpret_cast<const float4*>(a)[i];
  float4 y = reinterpret_cast<const float4*>(b)[i];
  reinterpret_cast<float4*>(o)[i] = make_float4(x.x + y.x, x.y + y.y, x.z + y.z, x.w + y.w);
}

extern "C" void kernel_launch(void* const* d_in, const int* in_sizes, int n_in,
                              void* d_out, int out_size, void* d_ws, size_t ws_size,
                              hipStream_t stream) {
  const int*   positions = (const int*)d_in[0];
  const float* hidden    = (const float*)d_in[1];
  const float* w_qkv     = (const float*)d_in[2];
  const float* w_o       = (const float*)d_in[3];
  const float* sinks     = (const float*)d_in[4];
  float* out = (float*)d_out;

  char* ws = (char*)d_ws;
  bf16*  wqkvT = (bf16*)(ws + 0);            // [5120][2944]  = 30,146,560 (dead after QKV)
  bf16*  woT   = (bf16*)(ws + 30146560);     // [2880][4160]  = 23,961,600
  bf16*  qb    = (bf16*)(ws + 54108160);     // [2048][4160]  = 17,039,360
  bf16*  kb    = (bf16*)(ws + 71147520);     // [2048][512]   =  2,097,152
  bf16*  vT    = (bf16*)(ws + 73244672);     // [16*64][1024] =  2,097,152
  bf16*  attnb = (bf16*)(ws + 75341824);     // [2048][4160]  = 17,039,360
  bf16*  hid_b = (bf16*)(ws + 92381184);     // [2048][2944]  = 12,058,624 (dead after QKV)
  float* cosT  = (float*)(ws + 104439808);   // 262,144 (dead after QKV)
  float* sinT  = (float*)(ws + 104701952);   // 262,144 (dead after QKV)
  float* Cp0   = (float*)(ws + 92381184);    // overlay hid_b/cosT/sinT
  float* Cp1   = (float*)(ws + 0);           // overlay wqkvT

  // 1. fused prep: w_qkv transpose + hidden cvt/pad + sincos tables
  prep_k<<<6880, 256, 0, stream>>>(w_qkv, wqkvT, hidden, hid_b, positions, cosT, sinT);
  // 2. QKV projection + fused RoPE/layout epilogue; tail blocks transpose w_o -> woT
  gemm256_k<2><<<160 + 1440, 512, 0, stream>>>(
      hid_b, wqkvT, nullptr, nullptr, qb, kb, vT, cosT, sinT, w_o, woT,
      QKVN, KPAD, QKVN / 256, KPAD / 128, 0);
  // 3. attention
  attn_k<<<2 * NH * (SEQ / 128), 256, 0, stream>>>(qb, kb, vT, sinks, attnb);
  // 4. output projection with 2-way K-split -> 2 f32 partials
  gemm256_k<0><<<2 * (NTOK / 256) * 12, 512, 0, stream>>>(
      attnb, woT, Cp0, Cp1, nullptr, nullptr, nullptr, nullptr, nullptr, nullptr, nullptr,
      HIDDEN, QST, 12, 16, 2048);
  // 5. partial sum -> out
  add2_k<<<(NTOK * HIDDEN / 4) / 256, 256, 0, stream>>>(Cp0, Cp1, out, NTOK * HIDDEN / 4);
}

// Round 10
// 217.829 us; speedup vs baseline: 1.6829x; 1.0301x over previous
//
#include <hip/hip_runtime.h>
#include <hip/hip_bf16.h>
#include <stdint.h>

typedef __hip_bfloat16 bf16;
typedef short bf16x8 __attribute__((ext_vector_type(8)));
typedef float f32x4 __attribute__((ext_vector_type(4)));

#define NTOK 2048
#define HIDDEN 2880
#define KPAD 2944
#define QKVN 5120
#define QSZ 4096
#define QST 4160   // padded row stride for qb/attnb/woT
#define NH 64
#define NKV 8
#define HD 64
#define SEQ 1024

__device__ __forceinline__ void gload16(const void* g, void* l) {
  __builtin_amdgcn_global_load_lds(
      (const __attribute__((address_space(1))) uint32_t*)g,
      (__attribute__((address_space(3))) uint32_t*)l, 16, 0, 0);
}

// =====================================================================================
// prep_k: (a) w_qkv transpose->bf16 [5120][2944], (b) hidden->bf16 padded [2048][2944],
// (c) sincos tables. blocks: [0,3680) transpose, [3680,6624) cvt, [6624,6880) sincos.
// =====================================================================================
__global__ __launch_bounds__(256) void prep_k(const float* __restrict__ w_qkv,
                                              bf16* __restrict__ wqkvT,
                                              const float* __restrict__ hidden,
                                              bf16* __restrict__ hid_b,
                                              const int* __restrict__ positions,
                                              float* __restrict__ cosT,
                                              float* __restrict__ sinT) {
  __shared__ float t[64][68];
  int bid = blockIdx.x, tid = threadIdx.x;
  if (bid < 3680) {
    int tx = bid % 80, ty = bid / 80;
    int c0 = tx * 64, r0 = ty * 64;
    int lr = tid >> 2, lc4 = (tid & 3) << 4;
    int r = r0 + lr;
    if (r < HIDDEN) {
      const float* s = w_qkv + (size_t)r * QKVN + c0 + lc4;
      *(float4*)&t[lr][lc4 + 0]  = *(const float4*)(s + 0);
      *(float4*)&t[lr][lc4 + 4]  = *(const float4*)(s + 4);
      *(float4*)&t[lr][lc4 + 8]  = *(const float4*)(s + 8);
      *(float4*)&t[lr][lc4 + 12] = *(const float4*)(s + 12);
    } else {
      float4 z = make_float4(0.f, 0.f, 0.f, 0.f);
      *(float4*)&t[lr][lc4 + 0]  = z; *(float4*)&t[lr][lc4 + 4]  = z;
      *(float4*)&t[lr][lc4 + 8]  = z; *(float4*)&t[lr][lc4 + 12] = z;
    }
    __syncthreads();
    int dr = tid >> 2;
#pragma unroll
    for (int rep = 0; rep < 2; ++rep) {
      int dc0 = (tid & 3) * 16 + rep * 8;
      bf16 o[8];
#pragma unroll
      for (int k = 0; k < 8; ++k) o[k] = __float2bfloat16(t[dc0 + k][dr]);
      *(uint4*)(wqkvT + (size_t)(c0 + dr) * KPAD + r0 + dc0) = *(const uint4*)o;
    }
  } else if (bid < 6624) {
    int gpr = KPAD >> 3;
    int i = (bid - 3680) * 256 + tid;
    if (i >= NTOK * gpr) return;
    int r = i / gpr, c8 = (i - r * gpr) << 3;
    bf16 o[8];
    if (c8 < HIDDEN) {
      const float4 v0 = *(const float4*)(hidden + (size_t)r * HIDDEN + c8);
      const float4 v1 = *(const float4*)(hidden + (size_t)r * HIDDEN + c8 + 4);
      o[0] = __float2bfloat16(v0.x); o[1] = __float2bfloat16(v0.y);
      o[2] = __float2bfloat16(v0.z); o[3] = __float2bfloat16(v0.w);
      o[4] = __float2bfloat16(v1.x); o[5] = __float2bfloat16(v1.y);
      o[6] = __float2bfloat16(v1.z); o[7] = __float2bfloat16(v1.w);
    } else {
#pragma unroll
      for (int j = 0; j < 8; ++j) o[j] = __float2bfloat16(0.f);
    }
    *(uint4*)(hid_b + (size_t)r * KPAD + c8) = *(const uint4*)o;
  } else {
    int i = (bid - 6624) * 256 + tid;
    int d = i >> 11, tt = i & 2047;
    float inv = powf(150000.0f, -(float)d / 32.0f);
    float a = (float)positions[tt] * inv;
    cosT[i] = cosf(a);
    sinT[i] = sinf(a);
  }
}

// =====================================================================================
// 256x256 8-phase bf16 GEMM (T2 swizzle + T3/T4 counted vmcnt + T5 setprio)
// R5/R6 proven body: per-quad LDA inside phase, lgkmcnt(0), no XCD swizzle.
// EPI=1: bf16 C partials (Cb0/Cb1 by ksplit half). EPI=2: fused RoPE epilogue +
// woT-transpose tail blocks.
// =====================================================================================
#define LDB(par) { \
  const char* _bb = lds + (((par)*4 + 2 + (wn>>1)) << 14); \
  _Pragma("unroll") \
  for (int _n = 0; _n < 4; ++_n) { \
    int _r = ((wn&1)<<6) + _n*16 + lm; \
    _Pragma("unroll") \
    for (int _kk = 0; _kk < 2; ++_kk) \
      bq[_n][_kk] = *(const bf16x8*)(_bb + _r*128 + (((_kk*4 + lg) ^ (_r & 7)) << 4)); } }

#define LDA(par, qc) { \
  const char* _ab = lds + (((par)*4 + wm) << 14); \
  _Pragma("unroll") \
  for (int _f = 0; _f < 2; ++_f) { \
    int _r = (qc)*32 + _f*16 + lm; \
    _Pragma("unroll") \
    for (int _kk = 0; _kk < 2; ++_kk) \
      af[_f][_kk] = *(const bf16x8*)(_ab + _r*128 + (((_kk*4 + lg) ^ (_r & 7)) << 4)); } }

#define MMQ(qc) \
  _Pragma("unroll") \
  for (int _kk = 0; _kk < 2; ++_kk) \
  _Pragma("unroll") \
  for (int _f = 0; _f < 2; ++_f) \
  _Pragma("unroll") \
  for (int _n = 0; _n < 4; ++_n) \
    acc[(qc)*2 + _f][_n] = __builtin_amdgcn_mfma_f32_16x16x32_bf16( \
        af[_f][_kk], bq[_n][_kk], acc[(qc)*2 + _f][_n], 0, 0, 0);

#define PHASE(qc, par, STMT, VMSTMT) { \
  bf16x8 af[2][2]; \
  if ((qc) == 0) { LDB(par); } \
  LDA(par, qc); \
  STMT \
  __builtin_amdgcn_s_barrier(); \
  asm volatile("s_waitcnt lgkmcnt(0)" ::: "memory"); \
  __builtin_amdgcn_sched_barrier(0); \
  __builtin_amdgcn_s_setprio(1); \
  MMQ(qc); \
  __builtin_amdgcn_s_setprio(0); \
  VMSTMT \
  __builtin_amdgcn_s_barrier(); }

template<int EPI>
__global__ __launch_bounds__(512, 2) void gemm256_k(
    const bf16* __restrict__ A, const bf16* __restrict__ BT,
    bf16* __restrict__ Cb0, bf16* __restrict__ Cb1,
    bf16* __restrict__ qb, bf16* __restrict__ kb, bf16* __restrict__ vT,
    const float* __restrict__ cosT, const float* __restrict__ sinT,
    const float* __restrict__ wo, bf16* __restrict__ woT,
    int N, int ldk, int nbn, int npair, int ksplit) {
  __shared__ __align__(16) char lds[131072];
  int tid = threadIdx.x;
  int bid = blockIdx.x;

  if (EPI == 2 && bid >= 160) {
    // ---- tail blocks: transpose w_o[4096][2880] -> woT[2880][QST], 2 tiles/block ----
    int i = bid - 160;
    int half = tid >> 8;
    int t = i * 2 + half;
    int tx = t % 45, ty = t / 45;
    int c0 = tx * 64, r0 = ty * 64;
    int tid2 = tid & 255;
    float* tb = (float*)lds + half * (64 * 68);
    int lr = tid2 >> 2, lc4 = (tid2 & 3) << 4;
    const float* s = wo + (size_t)(r0 + lr) * HIDDEN + c0 + lc4;
    *(float4*)&tb[lr * 68 + lc4 + 0]  = *(const float4*)(s + 0);
    *(float4*)&tb[lr * 68 + lc4 + 4]  = *(const float4*)(s + 4);
    *(float4*)&tb[lr * 68 + lc4 + 8]  = *(const float4*)(s + 8);
    *(float4*)&tb[lr * 68 + lc4 + 12] = *(const float4*)(s + 12);
    __syncthreads();
    int dr = tid2 >> 2;
#pragma unroll
    for (int rep = 0; rep < 2; ++rep) {
      int dc0 = (tid2 & 3) * 16 + rep * 8;
      bf16 o[8];
#pragma unroll
      for (int k = 0; k < 8; ++k) o[k] = __float2bfloat16(tb[(dc0 + k) * 68 + dr]);
      *(uint4*)(woT + (size_t)(c0 + dr) * QST + r0 + dc0) = *(const uint4*)o;
    }
    return;
  }

  int l = tid & 63, lg = l >> 4, lm = l & 15;
  int w = tid >> 6, wm = w >> 2, wn = w & 3;
  int kbeg = 0;
  bf16* Cb = Cb0;
  if (ksplit) {
    int half = gridDim.x >> 1;
    if (bid >= half) { bid -= half; kbeg = ksplit; Cb = Cb1; }
  }
  int bm = bid / nbn, bn = bid - bm * nbn;
  int m0 = bm << 8, n0 = bn << 8;
  int Bmax = N - 1;
  f32x4 acc[8][4] = {};
  bf16x8 bq[4][2];

  auto STG = [&](int slot, const bf16* mat, int rowBase, int rowMax, int kbase) {
#pragma unroll
    for (int rep = 0; rep < 2; ++rep) {
      int gi = (rep << 9) + tid;
      int row = gi >> 3, g = gi & 7;
      int gr = rowBase + row; if (gr > rowMax) gr = rowMax;
      gload16(mat + (size_t)gr * ldk + kbase + ((g ^ (row & 7)) << 3),
              lds + slot * 16384 + gi * 16);
    }
  };

  STG(0, A, m0, 2047, kbeg);
  STG(1, A, m0 + 128, 2047, kbeg);
  STG(2, BT, n0, Bmax, kbeg);
  STG(3, BT, n0 + 128, Bmax, kbeg);
  STG(6, BT, n0, Bmax, kbeg + 64);
  STG(7, BT, n0 + 128, Bmax, kbeg + 64);
  asm volatile("s_waitcnt vmcnt(4)" ::: "memory");
  __builtin_amdgcn_s_barrier();

  for (int i = 0; i < npair; ++i) {
    int kt = kbeg + (i << 7);
    bool pf = (i + 1 < npair);
    PHASE(0, 0, { STG(4, A, m0, 2047, kt + 64); }, ;)
    PHASE(1, 0, { STG(5, A, m0 + 128, 2047, kt + 64); }, ;)
    PHASE(2, 0, { if (pf) STG(2, BT, n0, Bmax, kt + 128); }, ;)
    PHASE(3, 0, { if (pf) STG(3, BT, n0 + 128, Bmax, kt + 128); },
          { if (pf) { asm volatile("s_waitcnt vmcnt(4)" ::: "memory"); }
            else    { asm volatile("s_waitcnt vmcnt(0)" ::: "memory"); } })
    PHASE(0, 1, { if (pf) STG(0, A, m0, 2047, kt + 128); }, ;)
    PHASE(1, 1, { if (pf) STG(1, A, m0 + 128, 2047, kt + 128); }, ;)
    PHASE(2, 1, { if (pf) STG(6, BT, n0, Bmax, kt + 192); }, ;)
    PHASE(3, 1, { if (pf) STG(7, BT, n0 + 128, Bmax, kt + 192); },
          { if (pf) { asm volatile("s_waitcnt vmcnt(4)" ::: "memory"); } })
  }

  if (EPI == 2) {
    // fused RoPE + layout epilogue. Wave owns head-slot h64 = bn*4 + wn.
    int h64 = (n0 >> 6) + wn;
    int tbase = m0 + (wm << 7) + lg * 4;
    if (h64 < 72) {
      bool isK = (h64 >= 64);
      bf16* outp = isK ? kb : qb;
      size_t ostr = isK ? 512 : QST;
      int hd0 = (isK ? (h64 - 64) : h64) << 6;
      float scl = isK ? 1.0f : 0.125f;
#pragma unroll
      for (int nf = 0; nf < 2; ++nf) {
        int d31 = nf * 16 + lm;
        const float* ct = cosT + (size_t)d31 * 2048;
        const float* st = sinT + (size_t)d31 * 2048;
#pragma unroll
        for (int mf = 0; mf < 8; ++mf) {
          int t0 = tbase + mf * 16;
          float4 c4 = *(const float4*)(ct + t0);
          float4 s4 = *(const float4*)(st + t0);
          float cc[4] = {c4.x, c4.y, c4.z, c4.w};
          float ss[4] = {s4.x, s4.y, s4.z, s4.w};
#pragma unroll
          for (int j = 0; j < 4; ++j) {
            float x1 = acc[mf][nf][j], x2 = acc[mf][nf + 2][j];
            outp[(size_t)(t0 + j) * ostr + hd0 + d31] =
                __float2bfloat16((x1 * cc[j] - x2 * ss[j]) * scl);
            outp[(size_t)(t0 + j) * ostr + hd0 + d31 + 32] =
                __float2bfloat16((x2 * cc[j] + x1 * ss[j]) * scl);
          }
        }
      }
    } else {
      int kvh = h64 - 72;
#pragma unroll
      for (int nf = 0; nf < 4; ++nf) {
        int d = nf * 16 + lm;
#pragma unroll
        for (int mf = 0; mf < 8; ++mf) {
          int t = tbase + mf * 16;          // j=0..3 are s-contiguous in vT
          int b = t >> 10, s = t & 1023;
          bf16 o[4];
#pragma unroll
          for (int j = 0; j < 4; ++j) o[j] = __float2bfloat16(acc[mf][nf][j]);
          *(uint2*)&vT[((size_t)(b * 8 + kvh) * 64 + d) * 1024 + s] = *(const uint2*)o;
        }
      }
    }
    return;
  }

  // EPI == 1: bf16 partial C
#pragma unroll
  for (int mf = 0; mf < 8; ++mf)
#pragma unroll
    for (int nf = 0; nf < 4; ++nf) {
      int col = n0 + (wn << 6) + nf * 16 + lm;
      if (col >= N) continue;
      int row = m0 + (wm << 7) + mf * 16 + lg * 4;
#pragma unroll
      for (int j = 0; j < 4; ++j)
        Cb[(size_t)(row + j) * N + col] = __float2bfloat16(acc[mf][nf][j]);
    }
}

// ---------------- flash attention, sliding window 128, sinks ----------------
__global__ __launch_bounds__(256) void attn_k(const bf16* __restrict__ Q,
                                              const bf16* __restrict__ Kg,
                                              const bf16* __restrict__ VT,
                                              const float* __restrict__ sinks,
                                              bf16* __restrict__ Og) {
  __shared__ __align__(16) bf16 Qs[128 * 64];
  __shared__ __align__(16) bf16 Ks[128 * 64];
  __shared__ __align__(16) bf16 Vs[64 * 128];
  __shared__ __align__(16) bf16 Ps[4][32 * 128];
  int bid = blockIdx.x;
  int b = bid >> 9, rest = bid & 511, h = rest >> 3, qt = rest & 7;
  int q0 = qt * 128, kvh = h >> 3;
  int tid = threadIdx.x, w = tid >> 6, l = tid & 63, lg = l >> 4, lm = l & 15;

  float mrun[2][4], lrun[2][4];
  float ls = __logf(sinks[h]);
#pragma unroll
  for (int mi = 0; mi < 2; ++mi)
#pragma unroll
    for (int j = 0; j < 4; ++j) { mrun[mi][j] = ls; lrun[mi][j] = 1.0f; }
  f32x4 oacc[2][4] = {};

#pragma unroll
  for (int g = 0; g < 4; ++g) {
    int c = g * 256 + w * 64 + l;
    int r = c >> 3, kc = (c & 7) * 8;
    gload16(Q + ((size_t)(b * 1024 + q0 + r)) * QST + h * 64 + kc,
            (char*)Qs + (size_t)(g * 256 + w * 64) * 16);
  }

  for (int t = (q0 == 0) ? 1 : 0; t < 2; ++t) {
    int kb = q0 - 128 + t * 128;
#pragma unroll
    for (int g = 0; g < 4; ++g) {
      int c = g * 256 + w * 64 + l;
      int r = c >> 3, kc = (c & 7) * 8;
      gload16(Kg + ((size_t)(b * 1024 + kb + r)) * 512 + kvh * 64 + kc,
              (char*)Ks + (size_t)(g * 256 + w * 64) * 16);
      int rv = c >> 4, kv = (c & 15) * 8;
      gload16(VT + ((size_t)(b * 8 + kvh) * 64 + rv) * 1024 + kb + kv,
              (char*)Vs + (size_t)(g * 256 + w * 64) * 16);
    }
    __syncthreads();

    f32x4 sacc[2][8] = {};
#pragma unroll
    for (int kk = 0; kk < 2; ++kk) {
      bf16x8 qf[2], kf[8];
#pragma unroll
      for (int mi = 0; mi < 2; ++mi)
        qf[mi] = *reinterpret_cast<const bf16x8*>(&Qs[(w * 32 + mi * 16 + lm) * 64 + kk * 32 + lg * 8]);
#pragma unroll
      for (int ni = 0; ni < 8; ++ni)
        kf[ni] = *reinterpret_cast<const bf16x8*>(&Ks[(ni * 16 + lm) * 64 + kk * 32 + lg * 8]);
#pragma unroll
      for (int mi = 0; mi < 2; ++mi)
#pragma unroll
        for (int ni = 0; ni < 8; ++ni)
          sacc[mi][ni] = __builtin_amdgcn_mfma_f32_16x16x32_bf16(qf[mi], kf[ni], sacc[mi][ni], 0, 0, 0);
    }

#pragma unroll
    for (int mi = 0; mi < 2; ++mi)
#pragma unroll
      for (int j = 0; j < 4; ++j) {
        int qi = q0 + w * 32 + mi * 16 + lg * 4 + j;
        float mx = -1e30f;
#pragma unroll
        for (int ni = 0; ni < 8; ++ni) {
          int kg = kb + ni * 16 + lm;
          float v = sacc[mi][ni][j];
          v = (kg <= qi && kg >= qi - 127) ? v : -1e30f;
          sacc[mi][ni][j] = v;
          mx = fmaxf(mx, v);
        }
#pragma unroll
        for (int d = 1; d < 16; d <<= 1) mx = fmaxf(mx, __shfl_xor(mx, d, 64));
        float mnew = fmaxf(mrun[mi][j], mx);
        float sum = 0.f;
#pragma unroll
        for (int ni = 0; ni < 8; ++ni) {
          float p = __expf(sacc[mi][ni][j] - mnew);
          sacc[mi][ni][j] = p;
          sum += p;
        }
#pragma unroll
        for (int d = 1; d < 16; d <<= 1) sum += __shfl_xor(sum, d, 64);
        float alpha = __expf(mrun[mi][j] - mnew);
        lrun[mi][j] = lrun[mi][j] * alpha + sum;
        mrun[mi][j] = mnew;
#pragma unroll
        for (int ni = 0; ni < 4; ++ni) oacc[mi][ni][j] *= alpha;
#pragma unroll
        for (int ni = 0; ni < 8; ++ni)
          Ps[w][(mi * 16 + lg * 4 + j) * 128 + ni * 16 + lm] = __float2bfloat16(sacc[mi][ni][j]);
      }

#pragma unroll
    for (int ks = 0; ks < 4; ++ks) {
      bf16x8 pf[2], vf[4];
#pragma unroll
      for (int mi = 0; mi < 2; ++mi)
        pf[mi] = *reinterpret_cast<const bf16x8*>(&Ps[w][(mi * 16 + lm) * 128 + ks * 32 + lg * 8]);
#pragma unroll
      for (int ni = 0; ni < 4; ++ni)
        vf[ni] = *reinterpret_cast<const bf16x8*>(&Vs[(ni * 16 + lm) * 128 + ks * 32 + lg * 8]);
#pragma unroll
      for (int mi = 0; mi < 2; ++mi)
#pragma unroll
        for (int ni = 0; ni < 4; ++ni)
          oacc[mi][ni] = __builtin_amdgcn_mfma_f32_16x16x32_bf16(pf[mi], vf[ni], oacc[mi][ni], 0, 0, 0);
    }
    __syncthreads();
  }

#pragma unroll
  for (int mi = 0; mi < 2; ++mi)
#pragma unroll
    for (int ni = 0; ni < 4; ++ni)
#pragma unroll
      for (int j = 0; j < 4; ++j) {
        int tok = b * 1024 + q0 + w * 32 + mi * 16 + lg * 4 + j;
        Og[(size_t)tok * QST + h * 64 + ni * 16 + lm] =
            __float2bfloat16(oacc[mi][ni][j] / lrun[mi][j]);
      }
}

// ---------------- add two bf16 partials -> f32 out ----------------
__global__ __launch_bounds__(256) void add2b_k(const bf16* __restrict__ a,
                                               const bf16* __restrict__ b,
                                               float* __restrict__ o, int n8) {
  int i = blockIdx.x * 256 + threadIdx.x;
  if (i >= n8) return;
  uint4 xa = reinterpret_cast<const uint4*>(a)[i];
  uint4 xb = reinterpret_cast<const uint4*>(b)[i];
  const bf16* pa = (const bf16*)&xa;
  const bf16* pb = (const bf16*)&xb;
  float r[8];
#pragma unroll
  for (int j = 0; j < 8; ++j) r[j] = __bfloat162float(pa[j]) + __bfloat162float(pb[j]);
  reinterpret_cast<float4*>(o)[i * 2]     = make_float4(r[0], r[1], r[2], r[3]);
  reinterpret_cast<float4*>(o)[i * 2 + 1] = make_float4(r[4], r[5], r[6], r[7]);
}

extern "C" void kernel_launch(void* const* d_in, const int* in_sizes, int n_in,
                              void* d_out, int out_size, void* d_ws, size_t ws_size,
                              hipStream_t stream) {
  const int*   positions = (const int*)d_in[0];
  const float* hidden    = (const float*)d_in[1];
  const float* w_qkv     = (const float*)d_in[2];
  const float* w_o       = (const float*)d_in[3];
  const float* sinks     = (const float*)d_in[4];
  float* out = (float*)d_out;

  char* ws = (char*)d_ws;
  bf16*  wqkvT = (bf16*)(ws + 0);            // [5120][2944]  = 30,146,560 (dead after QKV)
  bf16*  woT   = (bf16*)(ws + 30146560);     // [2880][4160]  = 23,961,600
  bf16*  qb    = (bf16*)(ws + 54108160);     // [2048][4160]  = 17,039,360 (dead after attn)
  bf16*  kb    = (bf16*)(ws + 71147520);     // [2048][512]   =  2,097,152
  bf16*  vT    = (bf16*)(ws + 73244672);     // [16*64][1024] =  2,097,152
  bf16*  attnb = (bf16*)(ws + 75341824);     // [2048][4160]  = 17,039,360
  bf16*  hid_b = (bf16*)(ws + 92381184);     // [2048][2944]  = 12,058,624 (dead after QKV)
  float* cosT  = (float*)(ws + 104439808);   // 262,144 (dead after QKV)
  float* sinT  = (float*)(ws + 104701952);   // 262,144 (dead after QKV)
  bf16*  Cp0b  = (bf16*)(ws + 54108160);     // overlay qb:    [2048][2880] bf16 = 11.8 MB
  bf16*  Cp1b  = (bf16*)(ws + 0);            // overlay wqkvT: [2048][2880] bf16 = 11.8 MB

  // 1. fused prep: w_qkv transpose + hidden cvt/pad + sincos tables
  prep_k<<<6880, 256, 0, stream>>>(w_qkv, wqkvT, hidden, hid_b, positions, cosT, sinT);
  // 2. QKV projection + fused RoPE/layout epilogue; tail blocks transpose w_o -> woT
  gemm256_k<2><<<160 + 1440, 512, 0, stream>>>(
      hid_b, wqkvT, nullptr, nullptr, qb, kb, vT, cosT, sinT, w_o, woT,
      QKVN, KPAD, QKVN / 256, KPAD / 128, 0);
  // 3. attention
  attn_k<<<2 * NH * (SEQ / 128), 256, 0, stream>>>(qb, kb, vT, sinks, attnb);
  // 4. output projection with 2-way K-split -> 2 bf16 partials
  gemm256_k<1><<<2 * (NTOK / 256) * 12, 512, 0, stream>>>(
      attnb, woT, Cp0b, Cp1b, nullptr, nullptr, nullptr, nullptr, nullptr, nullptr, nullptr,
      HIDDEN, QST, 12, 16, 2048);
  // 5. partial sum -> f32 out
  add2b_k<<<(NTOK * HIDDEN / 8) / 256, 256, 0, stream>>>(Cp0b, Cp1b, out, NTOK * HIDDEN / 8);
}